// Round 2
// baseline (675.290 us; speedup 1.0000x reference)
//
#include <hip/hip_runtime.h>
#include <hip/hip_bf16.h>
#include <cstdint>

#define S_LEN 2048
#define DMODEL 4096
#define NHEAD 32
#define NKV 8
#define HDIM 128
#define MAXSEQ 4096
#define NQKV 6144   // 4096 + 1024 + 1024

typedef __bf16 bf16x8 __attribute__((ext_vector_type(8)));
typedef float f32x4 __attribute__((ext_vector_type(4)));
typedef short s16x4 __attribute__((ext_vector_type(4)));

__device__ __forceinline__ short f2bf(float f) {
  unsigned u = __builtin_bit_cast(unsigned, f);
  u += 0x7fffu + ((u >> 16) & 1u);
  return (short)(u >> 16);
}

__device__ __forceinline__ void gload_lds16(const void* g, const void* l) {
  __builtin_amdgcn_global_load_lds((const __attribute__((address_space(1))) unsigned*)g,
                                   (__attribute__((address_space(3))) unsigned*)(l), 16, 0, 0);
}

// ---------------- RMSNorm: fp32 in -> bf16 out ----------------
__global__ __launch_bounds__(256) void rmsnorm_kernel(const float* __restrict__ x,
                                                      const float* __restrict__ w,
                                                      short* __restrict__ out) {
  const int row = blockIdx.x, tid = threadIdx.x;
  const float4* xr = (const float4*)(x + (size_t)row * DMODEL);
  const float4* wr = (const float4*)w;
  float4 v[4];
  float ss = 0.f;
#pragma unroll
  for (int i = 0; i < 4; ++i) {
    v[i] = xr[tid + i * 256];
    ss += v[i].x * v[i].x + v[i].y * v[i].y + v[i].z * v[i].z + v[i].w * v[i].w;
  }
#pragma unroll
  for (int m = 32; m; m >>= 1) ss += __shfl_down(ss, m, 64);
  __shared__ float red[4];
  if ((tid & 63) == 0) red[tid >> 6] = ss;
  __syncthreads();
  float tot = red[0] + red[1] + red[2] + red[3];
  float sc = rsqrtf(tot * (1.f / DMODEL) + 1e-5f);
#pragma unroll
  for (int i = 0; i < 4; ++i) {
    float4 wv = wr[tid + i * 256];
    s16x4 o;
    o[0] = f2bf(v[i].x * sc * wv.x);
    o[1] = f2bf(v[i].y * sc * wv.y);
    o[2] = f2bf(v[i].z * sc * wv.z);
    o[3] = f2bf(v[i].w * sc * wv.w);
    *(s16x4*)&out[(size_t)row * DMODEL + (size_t)(tid + i * 256) * 4] = o;
  }
}

// ---------------- cast fp32 (rows x cols) -> bf16 transposed (cols x rows) ----------------
__global__ __launch_bounds__(256) void cast_transpose(const float* __restrict__ src,
                                                      short* __restrict__ dst,
                                                      int rows, int cols) {
  __shared__ float tile[32][33];
  const int c0 = blockIdx.x * 32, r0 = blockIdx.y * 32;
  const int tx = threadIdx.x, ty = threadIdx.y;
#pragma unroll
  for (int i = ty; i < 32; i += 8) tile[i][tx] = src[(size_t)(r0 + i) * cols + c0 + tx];
  __syncthreads();
  const int tid = ty * 32 + tx;
#pragma unroll
  for (int rep = 0; rep < 2; ++rep) {
    int w = rep * 256 + tid;
    int i = w >> 4, pr = (w & 15) * 2;
    short2 o;
    o.x = f2bf(tile[pr][i]);
    o.y = f2bf(tile[pr + 1][i]);
    *(short2*)&dst[(size_t)(c0 + i) * rows + r0 + pr] = o;
  }
}

// ---------------- V transpose: QKV V-region fp32 -> vc fp32 (natural) + vt bf16 [g][d][s] ----------------
__global__ __launch_bounds__(256) void v_transpose(const float* __restrict__ QKV,
                                                   float* __restrict__ vc,
                                                   short* __restrict__ vt) {
  __shared__ float tile[32][33];
  const int d0 = blockIdx.x * 32, s0 = blockIdx.y * 32, g = blockIdx.z;
  const int tx = threadIdx.x, ty = threadIdx.y;
#pragma unroll
  for (int i = ty; i < 32; i += 8) {
    float v = QKV[(size_t)(s0 + i) * NQKV + (NHEAD + NKV) * HDIM + g * HDIM + d0 + tx];
    tile[i][tx] = v;
    vc[(size_t)(s0 + i) * (NKV * HDIM) + g * HDIM + d0 + tx] = v;
  }
  __syncthreads();
  const int tid = ty * 32 + tx;
#pragma unroll
  for (int rep = 0; rep < 2; ++rep) {
    int w = rep * 256 + tid;
    int i = w >> 4, pr = (w & 15) * 2;
    short2 o;
    o.x = f2bf(tile[pr][i]);
    o.y = f2bf(tile[pr + 1][i]);
    *(short2*)&vt[((size_t)g * HDIM + d0 + i) * S_LEN + s0 + pr] = o;
  }
}

// ================= 256x256 8-phase bf16 MFMA GEMM =================
// C(MxN fp32) = A(MxK bf16) * Bt(NxK bf16)^T (+ optional residual).
// 512 threads = 8 waves (2 M-waves x 4 N-waves); per-wave 128x64 output.
// BK=64, double-buffered 128KiB LDS, half-tile staging via global_load_lds,
// XOR-swizzled LDS (byte ^= (row&7)<<4), counted vmcnt, setprio on MFMA.
// Requires: M%256==0, N%256==0, K%128==0.

template<int KS, int MH>
__device__ __forceinline__ void ph_load(const short* __restrict__ AsH, const short* __restrict__ BsH,
                                        const int lrow, const int quad, const int brow0,
                                        bf16x8 (&aR)[4], bf16x8 (&bR)[2][4]) {
  const int xr = lrow & 7;
#pragma unroll
  for (int f = 0; f < 4; ++f)
    aR[f] = *(const bf16x8*)&AsH[((((MH * 4 + f) * 16 + lrow) * 8) + ((KS * 4 + quad) ^ xr)) * 8];
  if constexpr (KS == 0 && MH == 0) {
#pragma unroll
    for (int ks = 0; ks < 2; ++ks)
#pragma unroll
      for (int f = 0; f < 4; ++f)
        bR[ks][f] = *(const bf16x8*)&BsH[(((brow0 + f * 16 + lrow) * 8) + ((ks * 4 + quad) ^ xr)) * 8];
  }
}

template<int KS, int MH>
__device__ __forceinline__ void ph_mfma(bf16x8 (&aR)[4], bf16x8 (&bR)[2][4], f32x4 (&acc)[8][4]) {
#pragma unroll
  for (int f = 0; f < 4; ++f)
#pragma unroll
    for (int n = 0; n < 4; ++n)
      acc[MH * 4 + f][n] =
          __builtin_amdgcn_mfma_f32_16x16x32_bf16(aR[f], bR[KS][n], acc[MH * 4 + f][n], 0, 0, 0);
}

__global__ __launch_bounds__(512, 2) void gemm256(const short* __restrict__ A,
                                                  const short* __restrict__ Bt,
                                                  float* __restrict__ C,
                                                  const float* __restrict__ resid,
                                                  int M, int N, int K) {
  extern __shared__ __align__(16) short smem[];
  short* As = smem;           // 2 buf * 2 half * 8192 shorts = 64 KiB
  short* Bs = smem + 32768;   // same = 64 KiB
  const int tid = threadIdx.x;
  const int lane = tid & 63, wave = tid >> 6;
  const int wm = wave >> 2, wn = wave & 3;       // 2 x 4 waves
  const int lrow = lane & 15, quad = lane >> 4;
  const int bhalf = wn >> 1, brow0 = (wn & 1) * 64;
  const int m0 = blockIdx.y * 256, n0 = blockIdx.x * 256;
  const int srow = tid >> 3;                      // staging row (0..63)
  const int scol = ((tid & 7) ^ (srow & 7)) << 3; // pre-swizzled source col (shorts)
  const short* Ag = A + (size_t)m0 * K;
  const short* Bg = Bt + (size_t)n0 * K;
  const int nk = K >> 6;  // # of 64-wide K-tiles (even)

#define STAGE_A(b, h, kt) do { \
    const short* g_ = Ag + (size_t)((h) * 128 + srow) * K + (size_t)(kt) * 64 + scol; \
    short* l_ = As + ((b) * 2 + (h)) * 8192 + wave * 512; \
    gload_lds16(g_, l_); \
    gload_lds16(g_ + (size_t)64 * K, l_ + 4096); \
  } while (0)
#define STAGE_B(b, h, kt) do { \
    const short* g_ = Bg + (size_t)((h) * 128 + srow) * K + (size_t)(kt) * 64 + scol; \
    short* l_ = Bs + ((b) * 2 + (h)) * 8192 + wave * 512; \
    gload_lds16(g_, l_); \
    gload_lds16(g_ + (size_t)64 * K, l_ + 4096); \
  } while (0)
#define VW_NONE
#define VW_4 asm volatile("s_waitcnt vmcnt(4)" ::: "memory");
#define VW_COND if (more) { asm volatile("s_waitcnt vmcnt(4)" ::: "memory"); } \
                else      { asm volatile("s_waitcnt vmcnt(0)" ::: "memory"); }
#define PHASE(BUF, KS, MH, STMT, VW) \
  ph_load<KS, MH>(As + ((BUF) * 2 + wm) * 8192, Bs + ((BUF) * 2 + bhalf) * 8192, \
                  lrow, quad, brow0, aR, bR); \
  STMT; \
  VW \
  __builtin_amdgcn_s_barrier(); \
  asm volatile("s_waitcnt lgkmcnt(0)" ::: "memory"); \
  __builtin_amdgcn_s_setprio(1); \
  ph_mfma<KS, MH>(aR, bR, acc); \
  __builtin_amdgcn_s_setprio(0); \
  __builtin_amdgcn_s_barrier();

  f32x4 acc[8][4] = {};
  bf16x8 aR[4], bR[2][4];

  // ---- prologue: stage K-tile 0 (A+B) into buf0, K-tile 1's B into buf1 ----
  STAGE_A(0, 0, 0); STAGE_A(0, 1, 0);
  STAGE_B(0, 0, 0); STAGE_B(0, 1, 0);
  STAGE_B(1, 0, 1); STAGE_B(1, 1, 1);
  asm volatile("s_waitcnt vmcnt(4)" ::: "memory");  // buf0 (first 8 ops) landed
  __builtin_amdgcn_s_barrier();

  const int niter = nk >> 1;
  for (int i = 0; i < niter; ++i) {
    const int t = 2 * i;
    const bool more = (t + 2 < nk);
    PHASE(0, 0, 0, STAGE_A(1, 0, t + 1), VW_NONE)
    PHASE(0, 0, 1, STAGE_A(1, 1, t + 1), VW_NONE)
    PHASE(0, 1, 0, if (more) { STAGE_B(0, 0, t + 2); }, VW_NONE)
    PHASE(0, 1, 1, if (more) { STAGE_B(0, 1, t + 2); }, VW_COND)
    PHASE(1, 0, 0, if (more) { STAGE_A(0, 0, t + 2); }, VW_NONE)
    PHASE(1, 0, 1, if (more) { STAGE_A(0, 1, t + 2); }, VW_NONE)
    PHASE(1, 1, 0, if (more) { STAGE_B(1, 0, t + 3); }, VW_NONE)
    PHASE(1, 1, 1, if (more) { STAGE_B(1, 1, t + 3); }, VW_4)
  }

  // ---- epilogue ----
#pragma unroll
  for (int fm = 0; fm < 8; ++fm)
#pragma unroll
    for (int fn = 0; fn < 4; ++fn) {
      int row = m0 + wm * 128 + fm * 16 + quad * 4;
      int col = n0 + wn * 64 + fn * 16 + lrow;
#pragma unroll
      for (int r = 0; r < 4; ++r) {
        float v = acc[fm][fn][r];
        size_t o = (size_t)(row + r) * N + col;
        if (resid) v += resid[o];
        C[o] = v;
      }
    }
#undef STAGE_A
#undef STAGE_B
#undef VW_NONE
#undef VW_4
#undef VW_COND
#undef PHASE
}

// ---------------- RoPE (interleaved) for Q and K, vectorized; writes q_bf, k_bf, kc ----------------
// Also zeroes the cache tail rows [S_LEN, MAXSEQ): grid*block == tail float4 count exactly.
__global__ __launch_bounds__(256) void rope_kernel(const float* __restrict__ QKV,
                                                   const float* __restrict__ cosb,
                                                   const float* __restrict__ sinb,
                                                   short* __restrict__ qo,
                                                   short* __restrict__ ko,
                                                   float* __restrict__ kc,
                                                   float* __restrict__ vc) {
  const int s = blockIdx.x, tid = threadIdx.x;
  const float4* r4 = (const float4*)(QKV + (size_t)s * NQKV);
  const float qscale = 0.08838834764831845f;  // 1/sqrt(128) folded into Q
#pragma unroll
  for (int it = 0; it < 5; ++it) {
    int i = it * 256 + tid;
    float4 x = r4[i];
    int e = i * 4;            // flat float index within row
    int d = e & 127;          // dim within head (heads are 128-aligned)
    float4 c = *(const float4*)&cosb[(size_t)s * HDIM + d];
    float4 si = *(const float4*)&sinb[(size_t)s * HDIM + d];
    float o0 = x.x * c.x - x.y * si.x;
    float o1 = x.y * c.y + x.x * si.y;
    float o2 = x.z * c.z - x.w * si.z;
    float o3 = x.w * c.w + x.z * si.w;
    if (e < NHEAD * HDIM) {
      int hh = e >> 7;
      s16x4 ov;
      ov[0] = f2bf(o0 * qscale); ov[1] = f2bf(o1 * qscale);
      ov[2] = f2bf(o2 * qscale); ov[3] = f2bf(o3 * qscale);
      *(s16x4*)&qo[((size_t)hh * S_LEN + s) * HDIM + d] = ov;
    } else {
      int ek = e - NHEAD * HDIM;
      int g = ek >> 7;
      s16x4 ov;
      ov[0] = f2bf(o0); ov[1] = f2bf(o1); ov[2] = f2bf(o2); ov[3] = f2bf(o3);
      *(s16x4*)&ko[((size_t)g * S_LEN + s) * HDIM + d] = ov;
      *(float4*)&kc[(size_t)s * (NKV * HDIM) + ek] = make_float4(o0, o1, o2, o3);
    }
  }
  // zero cache tails: tail float4 count = (MAXSEQ-S_LEN)*NKV*HDIM/4 = 524288 = 2048*256
  {
    const size_t base = (size_t)S_LEN * NKV * HDIM;
    const size_t i = (size_t)s * 256 + tid;
    const float4 z = make_float4(0.f, 0.f, 0.f, 0.f);
    ((float4*)(kc + base))[i] = z;
    ((float4*)(vc + base))[i] = z;
  }
}

// ---------------- GQA causal flash attention v2 ----------------
#define TKEY 128
__global__ __launch_bounds__(256, 1) void attn_kernel(const short* __restrict__ Q,
                                                      const short* __restrict__ Kb,
                                                      const short* __restrict__ Vt,
                                                      short* __restrict__ out) {
  extern __shared__ __align__(16) short smem[];
  short* Ks = smem;            // 2 * 128*128
  short* Vs = smem + 32768;    // 2 * 128*128
  short* Ps = smem + 65536;    // 4 waves * 32*32
  const int tid = threadIdx.x;
  const int lane = tid & 63, wave = tid >> 6;
  const int lrow = lane & 15, quad = lane >> 4;
  const int g = blockIdx.x & 7, p = blockIdx.x >> 3;
  const int h = g * 4 + wave;
  const float L2E = 1.44269504f;
  const short* Kg = Kb + (size_t)g * S_LEN * HDIM;
  const short* Vg = Vt + (size_t)g * HDIM * S_LEN;
  short* Pw = Ps + wave * 1024;

#pragma unroll 1
  for (int ph = 0; ph < 2; ++ph) {
    const int qt = ph ? (63 - p) : p;
    const int nt = (qt >> 2) + 1;  // # of 128-key tiles

    bf16x8 qf[2][4];
#pragma unroll
    for (int i = 0; i < 2; ++i)
#pragma unroll
      for (int kf = 0; kf < 4; ++kf)
        qf[i][kf] = *(const bf16x8*)&Q[((size_t)h * S_LEN + qt * 32 + i * 16 + lrow) * HDIM + kf * 32 + quad * 8];

    f32x4 O[2][8] = {};
    float mrun[2][4], lrun[2][4];
#pragma unroll
    for (int i = 0; i < 2; ++i)
#pragma unroll
      for (int r = 0; r < 4; ++r) { mrun[i][r] = -1e30f; lrun[i][r] = 0.f; }

    // stage tile 0 into buffer 0
#pragma unroll
    for (int ii = 0; ii < 8; ++ii) {
      int s = (wave * 8 + ii) * 64 + lane;
      int r = s >> 4, gg = (s & 15) ^ (r & 15);
      gload_lds16(Kg + (size_t)r * HDIM + gg * 8, Ks + (wave * 8 + ii) * 512);
    }
#pragma unroll
    for (int ii = 0; ii < 8; ++ii) {
      int s = (wave * 8 + ii) * 64 + lane;
      int d = s >> 4, kg = (s & 15) ^ (d & 15);
      gload_lds16(Vg + (size_t)d * S_LEN + kg * 8, Vs + (wave * 8 + ii) * 512);
    }
    __syncthreads();

#pragma unroll 1
    for (int t = 0; t < nt; ++t) {
      const int bsel = t & 1;
      if (t + 1 < nt) {
        const int kb2 = (t + 1) * TKEY, o = (1 - bsel) * 16384;
#pragma unroll
        for (int ii = 0; ii < 8; ++ii) {
          int s = (wave * 8 + ii) * 64 + lane;
          int r = s >> 4, gg = (s & 15) ^ (r & 15);
          gload_lds16(Kg + (size_t)(kb2 + r) * HDIM + gg * 8, Ks + o + (wave * 8 + ii) * 512);
        }
#pragma unroll
        for (int ii = 0; ii < 8; ++ii) {
          int s = (wave * 8 + ii) * 64 + lane;
          int d = s >> 4, kg = (s & 15) ^ (d & 15);
          gload_lds16(Vg + (size_t)d * S_LEN + kb2 + kg * 8, Vs + o + (wave * 8 + ii) * 512);
        }
      }
      const short* Kc = Ks + bsel * 16384;
      const short* Vc = Vs + bsel * 16384;

      // ---- QK^T: 32 rows x 128 keys ----
      f32x4 sc[2][8] = {};
#pragma unroll
      for (int c = 0; c < 8; ++c) {
        int r = c * 16 + lrow;
#pragma unroll
        for (int kf = 0; kf < 4; ++kf) {
          int slot = r * 16 + ((kf * 4 + quad) ^ lrow);
          bf16x8 kfr = *(const bf16x8*)&Kc[slot * 8];
          sc[0][c] = __builtin_amdgcn_mfma_f32_16x16x32_bf16(qf[0][kf], kfr, sc[0][c], 0, 0, 0);
          sc[1][c] = __builtin_amdgcn_mfma_f32_16x16x32_bf16(qf[1][kf], kfr, sc[1][c], 0, 0, 0);
        }
      }

      // ---- online softmax ----
      const int kb = t * TKEY;
      const bool last = (t == nt - 1);
#pragma unroll
      for (int i = 0; i < 2; ++i) {
        if (last) {
#pragma unroll
          for (int c = 0; c < 8; ++c) {
            int key = kb + c * 16 + lrow;
#pragma unroll
            for (int r = 0; r < 4; ++r) {
              int row = qt * 32 + i * 16 + quad * 4 + r;
              if (key > row) sc[i][c][r] = -1e30f;
            }
          }
        }
        float tm[4];
#pragma unroll
        for (int r = 0; r < 4; ++r) tm[r] = sc[i][0][r];
#pragma unroll
        for (int c = 1; c < 8; ++c)
#pragma unroll
          for (int r = 0; r < 4; ++r) tm[r] = fmaxf(tm[r], sc[i][c][r]);
#pragma unroll
        for (int msk = 1; msk <= 8; msk <<= 1)
#pragma unroll
          for (int r = 0; r < 4; ++r) tm[r] = fmaxf(tm[r], __shfl_xor(tm[r], msk, 64));
#pragma unroll
        for (int r = 0; r < 4; ++r) {
          float nm = fmaxf(mrun[i][r], tm[r]);
          float alpha = exp2f((mrun[i][r] - nm) * L2E);
          mrun[i][r] = nm;
          lrun[i][r] *= alpha;
#pragma unroll
          for (int jd = 0; jd < 8; ++jd) O[i][jd][r] *= alpha;
        }
        float rs[4] = {0.f, 0.f, 0.f, 0.f};
#pragma unroll
        for (int c = 0; c < 8; ++c)
#pragma unroll
          for (int r = 0; r < 4; ++r) {
            float pv = exp2f((sc[i][c][r] - mrun[i][r]) * L2E);
            sc[i][c][r] = pv;
            rs[r] += pv;
          }
#pragma unroll
        for (int msk = 1; msk <= 8; msk <<= 1)
#pragma unroll
          for (int r = 0; r < 4; ++r) rs[r] += __shfl_xor(rs[r], msk, 64);
#pragma unroll
        for (int r = 0; r < 4; ++r) lrun[i][r] += rs[r];
      }

      // ---- P·V in 32-key chunks ----
#pragma unroll
      for (int ks = 0; ks < 4; ++ks) {
#pragma unroll
        for (int i = 0; i < 2; ++i)
#pragma unroll
          for (int cc = 0; cc < 2; ++cc) {
            int c = ks * 2 + cc;
            int kg = cc * 2 + (lrow >> 3), off = lrow & 7;
#pragma unroll
            for (int r = 0; r < 4; ++r) {
              int q2 = i * 16 + quad * 4 + r;
              int slot = q2 * 4 + (kg ^ (q2 & 3) ^ ((q2 >> 2) & 3));
              Pw[slot * 8 + off] = f2bf(sc[i][c][r]);
            }
          }
        bf16x8 pa[2];
#pragma unroll
        for (int i = 0; i < 2; ++i) {
          int q2 = i * 16 + lrow;
          int slot = q2 * 4 + (quad ^ (q2 & 3) ^ ((q2 >> 2) & 3));
          pa[i] = *(const bf16x8*)&Pw[slot * 8];
        }
#pragma unroll
        for (int jd = 0; jd < 8; ++jd) {
          int d = jd * 16 + lrow;
          int slotv = d * 16 + ((ks * 4 + quad) ^ lrow);
          bf16x8 vb = *(const bf16x8*)&Vc[slotv * 8];
          O[0][jd] = __builtin_amdgcn_mfma_f32_16x16x32_bf16(pa[0], vb, O[0][jd], 0, 0, 0);
          O[1][jd] = __builtin_amdgcn_mfma_f32_16x16x32_bf16(pa[1], vb, O[1][jd], 0, 0, 0);
        }
      }
      __syncthreads();
    }

    // ---- epilogue ----
#pragma unroll
    for (int i = 0; i < 2; ++i)
#pragma unroll
      for (int r = 0; r < 4; ++r) {
        float inv = 1.f / lrun[i][r];
        int row = qt * 32 + i * 16 + quad * 4 + r;
#pragma unroll
        for (int jd = 0; jd < 8; ++jd)
          out[(size_t)row * DMODEL + h * HDIM + jd * 16 + lrow] = f2bf(O[i][jd][r] * inv);
      }
    __syncthreads();  // Ks/Vs safe for next phase's staging
  }
}

extern "C" void kernel_launch(void* const* d_in, const int* in_sizes, int n_in,
                              void* d_out, int out_size, void* d_ws, size_t ws_size,
                              hipStream_t stream) {
  const float* hs   = (const float*)d_in[0];
  const float* cosb = (const float*)d_in[1];
  const float* sinb = (const float*)d_in[2];
  const float* Wq   = (const float*)d_in[5];
  const float* Wk   = (const float*)d_in[6];
  const float* Wv   = (const float*)d_in[7];
  const float* Wo   = (const float*)d_in[8];
  const float* rmsw = (const float*)d_in[9];

  float* outp = (float*)d_out;
  float* kc = outp + (size_t)S_LEN * DMODEL;
  float* vc = kc + (size_t)MAXSEQ * NKV * HDIM;

  char* p = (char*)d_ws;
  short* h_bf  = (short*)p; p += (size_t)S_LEN * DMODEL * 2;
  short* WqkvT = (short*)p; p += (size_t)NQKV * DMODEL * 2;
  short* WoT   = (short*)p; p += (size_t)DMODEL * DMODEL * 2;
  float* QKV   = (float*)p; p += (size_t)S_LEN * NQKV * 4;
  short* q_bf  = (short*)p; p += (size_t)NHEAD * S_LEN * HDIM * 2;
  short* k_bf  = (short*)p; p += (size_t)NKV * S_LEN * HDIM * 2;
  short* vt_bf = (short*)p; p += (size_t)NKV * HDIM * S_LEN * 2;
  short* attn_bf = h_bf;  // alias: h consumed by gemm1 before attention writes

  const int ATTN_LDS = 139264;  // 64KB K dbuf + 64KB V dbuf + 8KB P
  hipFuncSetAttribute(reinterpret_cast<const void*>(attn_kernel),
                      hipFuncAttributeMaxDynamicSharedMemorySize, ATTN_LDS);
  const int GEMM_LDS = 131072;  // 2buf x (A 32KB + B 32KB)
  hipFuncSetAttribute(reinterpret_cast<const void*>(gemm256),
                      hipFuncAttributeMaxDynamicSharedMemorySize, GEMM_LDS);

  rmsnorm_kernel<<<S_LEN, 256, 0, stream>>>(hs, rmsw, h_bf);
  cast_transpose<<<dim3(DMODEL / 32, DMODEL / 32), dim3(32, 8), 0, stream>>>(Wq, WqkvT, DMODEL, DMODEL);
  cast_transpose<<<dim3(1024 / 32, DMODEL / 32), dim3(32, 8), 0, stream>>>(Wk, WqkvT + (size_t)DMODEL * DMODEL, DMODEL, 1024);
  cast_transpose<<<dim3(1024 / 32, DMODEL / 32), dim3(32, 8), 0, stream>>>(Wv, WqkvT + (size_t)5120 * DMODEL, DMODEL, 1024);
  cast_transpose<<<dim3(DMODEL / 32, DMODEL / 32), dim3(32, 8), 0, stream>>>(Wo, WoT, DMODEL, DMODEL);
  gemm256<<<dim3(NQKV / 256, S_LEN / 256), 512, GEMM_LDS, stream>>>(h_bf, WqkvT, QKV, nullptr, S_LEN, NQKV, DMODEL);
  rope_kernel<<<S_LEN, 256, 0, stream>>>(QKV, cosb, sinb, q_bf, k_bf, kc, vc);
  v_transpose<<<dim3(HDIM / 32, S_LEN / 32, NKV), dim3(32, 8), 0, stream>>>(QKV, vc, vt_bf);
  attn_kernel<<<256, 256, ATTN_LDS, stream>>>(q_bf, k_bf, vt_bf, attn_bf);
  gemm256<<<dim3(DMODEL / 256, S_LEN / 256), 512, GEMM_LDS, stream>>>(attn_bf, WoT, outp, hs, S_LEN, DMODEL, DMODEL);
}

// Round 3
// 586.670 us; speedup vs baseline: 1.1511x; 1.1511x over previous
//
#include <hip/hip_runtime.h>
#include <hip/hip_bf16.h>
#include <cstdint>

#define S_LEN 2048
#define DMODEL 4096
#define NHEAD 32
#define NKV 8
#define HDIM 128
#define MAXSEQ 4096
#define NQKV 6144   // 4096 + 1024 + 1024

typedef __bf16 bf16x8 __attribute__((ext_vector_type(8)));
typedef float f32x4 __attribute__((ext_vector_type(4)));
typedef short s16x4 __attribute__((ext_vector_type(4)));

__device__ __forceinline__ short f2bf(float f) {
  unsigned u = __builtin_bit_cast(unsigned, f);
  u += 0x7fffu + ((u >> 16) & 1u);
  return (short)(u >> 16);
}

__device__ __forceinline__ void gload_lds16(const void* g, const void* l) {
  __builtin_amdgcn_global_load_lds((const __attribute__((address_space(1))) unsigned*)g,
                                   (__attribute__((address_space(3))) unsigned*)(l), 16, 0, 0);
}

template<int N> __device__ __forceinline__ void vwait() {
  if constexpr (N == 0) asm volatile("s_waitcnt vmcnt(0)" ::: "memory");
  else if constexpr (N == 1) asm volatile("s_waitcnt vmcnt(1)" ::: "memory");
  else if constexpr (N == 2) asm volatile("s_waitcnt vmcnt(2)" ::: "memory");
  else if constexpr (N == 3) asm volatile("s_waitcnt vmcnt(3)" ::: "memory");
  else if constexpr (N == 4) asm volatile("s_waitcnt vmcnt(4)" ::: "memory");
}

// ---------------- RMSNorm: fp32 in -> bf16 out ----------------
__global__ __launch_bounds__(256) void rmsnorm_kernel(const float* __restrict__ x,
                                                      const float* __restrict__ w,
                                                      short* __restrict__ out) {
  const int row = blockIdx.x, tid = threadIdx.x;
  const float4* xr = (const float4*)(x + (size_t)row * DMODEL);
  const float4* wr = (const float4*)w;
  float4 v[4];
  float ss = 0.f;
#pragma unroll
  for (int i = 0; i < 4; ++i) {
    v[i] = xr[tid + i * 256];
    ss += v[i].x * v[i].x + v[i].y * v[i].y + v[i].z * v[i].z + v[i].w * v[i].w;
  }
#pragma unroll
  for (int m = 32; m; m >>= 1) ss += __shfl_down(ss, m, 64);
  __shared__ float red[4];
  if ((tid & 63) == 0) red[tid >> 6] = ss;
  __syncthreads();
  float tot = red[0] + red[1] + red[2] + red[3];
  float sc = rsqrtf(tot * (1.f / DMODEL) + 1e-5f);
#pragma unroll
  for (int i = 0; i < 4; ++i) {
    float4 wv = wr[tid + i * 256];
    s16x4 o;
    o[0] = f2bf(v[i].x * sc * wv.x);
    o[1] = f2bf(v[i].y * sc * wv.y);
    o[2] = f2bf(v[i].z * sc * wv.z);
    o[3] = f2bf(v[i].w * sc * wv.w);
    *(s16x4*)&out[(size_t)row * DMODEL + (size_t)(tid + i * 256) * 4] = o;
  }
}

// ---------------- fused cast+transpose of all 4 weights (fp32 KxN -> bf16 NxK) ----------------
// grid (128, 128, 4), block (32, 8). z selects weight; narrow weights early-exit extra x-blocks.
__global__ __launch_bounds__(256) void cast_transpose_all(const float* __restrict__ Wq,
                                                          const float* __restrict__ Wk,
                                                          const float* __restrict__ Wv,
                                                          const float* __restrict__ Wo,
                                                          short* __restrict__ WqkvT,
                                                          short* __restrict__ WoT) {
  const int z = blockIdx.z;
  const float* src;
  short* dst;
  int cols;
  if (z == 0)      { src = Wq; dst = WqkvT;                            cols = 4096; }
  else if (z == 1) { src = Wk; dst = WqkvT + (size_t)4096 * 4096;      cols = 1024; }
  else if (z == 2) { src = Wv; dst = WqkvT + (size_t)5120 * 4096;      cols = 1024; }
  else             { src = Wo; dst = WoT;                              cols = 4096; }
  const int c0 = blockIdx.x * 32, r0 = blockIdx.y * 32;
  if (c0 >= cols) return;  // uniform per block
  __shared__ float tile[32][33];
  const int tx = threadIdx.x, ty = threadIdx.y;
#pragma unroll
  for (int i = ty; i < 32; i += 8) tile[i][tx] = src[(size_t)(r0 + i) * cols + c0 + tx];
  __syncthreads();
  const int tid = ty * 32 + tx;
#pragma unroll
  for (int rep = 0; rep < 2; ++rep) {
    int w = rep * 256 + tid;
    int i = w >> 4, pr = (w & 15) * 2;
    short2 o;
    o.x = f2bf(tile[pr][i]);
    o.y = f2bf(tile[pr + 1][i]);
    *(short2*)&dst[(size_t)(c0 + i) * 4096 + r0 + pr] = o;
  }
}

// ---------------- V transpose: QKV V-region fp32 -> vc fp32 (natural) + vt bf16 [g][d][s] ----------------
__global__ __launch_bounds__(256) void v_transpose(const float* __restrict__ QKV,
                                                   float* __restrict__ vc,
                                                   short* __restrict__ vt) {
  __shared__ float tile[32][33];
  const int d0 = blockIdx.x * 32, s0 = blockIdx.y * 32, g = blockIdx.z;
  const int tx = threadIdx.x, ty = threadIdx.y;
#pragma unroll
  for (int i = ty; i < 32; i += 8) {
    float v = QKV[(size_t)(s0 + i) * NQKV + (NHEAD + NKV) * HDIM + g * HDIM + d0 + tx];
    tile[i][tx] = v;
    vc[(size_t)(s0 + i) * (NKV * HDIM) + g * HDIM + d0 + tx] = v;
  }
  __syncthreads();
  const int tid = ty * 32 + tx;
#pragma unroll
  for (int rep = 0; rep < 2; ++rep) {
    int w = rep * 256 + tid;
    int i = w >> 4, pr = (w & 15) * 2;
    short2 o;
    o.x = f2bf(tile[pr][i]);
    o.y = f2bf(tile[pr + 1][i]);
    *(short2*)&vt[((size_t)g * HDIM + d0 + i) * S_LEN + s0 + pr] = o;
  }
}

// ================= 256 x (64*NF) 8-phase bf16 MFMA GEMM =================
// C(MxN fp32) = A(MxK bf16) * Bt(NxK bf16)^T (+ optional residual).
// 512 threads = 8 waves (2 M-waves x 4 N-waves); per-wave 128 x (16*NF) output.
// BK=64, double-buffered LDS (A 64KB + B NF*32KB... shorts), XOR-swizzled granules,
// counted vmcnt(NF), setprio on MFMA.  Requires: M%256==0, N%(64*NF)==0, K%128==0.

template<int NF, int KS, int MH>
__device__ __forceinline__ void ph_load(const short* __restrict__ AsH, const short* __restrict__ BsB,
                                        const int lrow, const int quad, const int wn,
                                        bf16x8 (&aR)[4], bf16x8 (&bR)[2][NF]) {
  const int xr = lrow & 7;
#pragma unroll
  for (int f = 0; f < 4; ++f)
    aR[f] = *(const bf16x8*)&AsH[((((MH * 4 + f) * 16 + lrow) * 8) + ((KS * 4 + quad) ^ xr)) * 8];
  if constexpr (MH == 0) {  // bR[KS] loaded at the first phase of each KS
#pragma unroll
    for (int f = 0; f < NF; ++f) {
      int rB = wn * (16 * NF) + f * 16 + lrow;
      bR[KS][f] = *(const bf16x8*)&BsB[((rB * 8) + ((KS * 4 + quad) ^ xr)) * 8];
    }
  }
}

template<int NF, int KS, int MH>
__device__ __forceinline__ void ph_mfma(bf16x8 (&aR)[4], bf16x8 (&bR)[2][NF], f32x4 (&acc)[8][NF]) {
#pragma unroll
  for (int f = 0; f < 4; ++f)
#pragma unroll
    for (int n = 0; n < NF; ++n)
      acc[MH * 4 + f][n] =
          __builtin_amdgcn_mfma_f32_16x16x32_bf16(aR[f], bR[KS][n], acc[MH * 4 + f][n], 0, 0, 0);
}

template<int NF>
__global__ __launch_bounds__(512, 2) void gemm256(const short* __restrict__ A,
                                                  const short* __restrict__ Bt,
                                                  float* __restrict__ C,
                                                  const float* __restrict__ resid,
                                                  int M, int N, int K) {
  extern __shared__ __align__(16) short smem[];
  short* As = smem;           // 2 buf * 2 half * 8192 shorts = 64 KiB
  short* Bs = smem + 32768;   // 2 buf * NF granules * 4096 shorts
  const int tid = threadIdx.x;
  const int lane = tid & 63, wave = tid >> 6;
  const int wm = wave >> 2, wn = wave & 3;       // 2 x 4 waves
  const int lrow = lane & 15, quad = lane >> 4;
  const int m0 = blockIdx.y * 256, n0 = blockIdx.x * (64 * NF);
  const int srow = tid >> 3;                      // staging row (0..63)
  const int scol = ((tid & 7) ^ (srow & 7)) << 3; // pre-swizzled source col (shorts)
  const short* Ag = A + (size_t)m0 * K;
  const short* Bg = Bt + (size_t)n0 * K;
  const int nk = K >> 6;  // # of 64-wide K-tiles (even)
  constexpr int G1 = NF - (NF >> 1);  // B granules staged at ph3/ph7
  constexpr int G2 = NF >> 1;         // B granules staged at ph4/ph8

#define STAGE_A(b, h, kt) do { \
    const short* g_ = Ag + (size_t)((h) * 128 + srow) * K + (size_t)(kt) * 64 + scol; \
    short* l_ = As + ((b) * 2 + (h)) * 8192 + wave * 512; \
    gload_lds16(g_, l_); \
    gload_lds16(g_ + (size_t)64 * K, l_ + 4096); \
  } while (0)
#define STAGE_BG(b, gr, kt) do { \
    const short* g_ = Bg + (size_t)((gr) * 64 + srow) * K + (size_t)(kt) * 64 + scol; \
    short* l_ = Bs + (b) * (NF * 4096) + (gr) * 4096 + wave * 512; \
    gload_lds16(g_, l_); \
  } while (0)
#define VW_COND if (more) { vwait<NF>(); } else { vwait<0>(); }
#define PHASE(BUF, KS, MH, STMT, VW) \
  ph_load<NF, KS, MH>(As + ((BUF) * 2 + wm) * 8192, Bs + (BUF) * (NF * 4096), \
                      lrow, quad, wn, aR, bR); \
  STMT; \
  VW \
  __builtin_amdgcn_s_barrier(); \
  asm volatile("s_waitcnt lgkmcnt(0)" ::: "memory"); \
  __builtin_amdgcn_s_setprio(1); \
  ph_mfma<NF, KS, MH>(aR, bR, acc); \
  __builtin_amdgcn_s_setprio(0); \
  __builtin_amdgcn_s_barrier();

  f32x4 acc[8][NF] = {};
  bf16x8 aR[4], bR[2][NF];

  // ---- prologue: buf0 = K-tile 0 (A+B); buf1.B = K-tile 1 ----
  STAGE_A(0, 0, 0); STAGE_A(0, 1, 0);
#pragma unroll
  for (int g = 0; g < NF; ++g) STAGE_BG(0, g, 0);
#pragma unroll
  for (int g = 0; g < NF; ++g) STAGE_BG(1, g, 1);
  vwait<NF>();  // buf0 (first 4+NF loads) landed
  __builtin_amdgcn_s_barrier();

  const int niter = nk >> 1;
  for (int i = 0; i < niter; ++i) {
    const int t = 2 * i;
    const bool more = (t + 2 < nk);
    PHASE(0, 0, 0, STAGE_A(1, 0, t + 1), )
    PHASE(0, 0, 1, STAGE_A(1, 1, t + 1), )
    PHASE(0, 1, 0,
          if (more) { _Pragma("unroll") for (int g = 0; g < G1; ++g) STAGE_BG(0, g, t + 2); }, )
    PHASE(0, 1, 1,
          if (more) { _Pragma("unroll") for (int g = G1; g < NF; ++g) STAGE_BG(0, g, t + 2); },
          VW_COND)
    PHASE(1, 0, 0, if (more) { STAGE_A(0, 0, t + 2); }, )
    PHASE(1, 0, 1, if (more) { STAGE_A(0, 1, t + 2); }, )
    PHASE(1, 1, 0,
          if (more) { _Pragma("unroll") for (int g = 0; g < G1; ++g) STAGE_BG(1, g, t + 3); }, )
    PHASE(1, 1, 1,
          if (more) { _Pragma("unroll") for (int g = G1; g < NF; ++g) STAGE_BG(1, g, t + 3); },
          vwait<NF>();)
  }

  // ---- epilogue ----
#pragma unroll
  for (int fm = 0; fm < 8; ++fm)
#pragma unroll
    for (int fn = 0; fn < NF; ++fn) {
      int row = m0 + wm * 128 + fm * 16 + quad * 4;
      int col = n0 + wn * (16 * NF) + fn * 16 + lrow;
#pragma unroll
      for (int r = 0; r < 4; ++r) {
        float v = acc[fm][fn][r];
        size_t o = (size_t)(row + r) * N + col;
        if (resid) v += resid[o];
        C[o] = v;
      }
    }
#undef STAGE_A
#undef STAGE_BG
#undef VW_COND
#undef PHASE
}

// ---------------- RoPE (interleaved) for Q and K, vectorized; writes q_bf, k_bf, kc ----------------
// Also zeroes the cache tail rows [S_LEN, MAXSEQ): grid*block == tail float4 count exactly.
__global__ __launch_bounds__(256) void rope_kernel(const float* __restrict__ QKV,
                                                   const float* __restrict__ cosb,
                                                   const float* __restrict__ sinb,
                                                   short* __restrict__ qo,
                                                   short* __restrict__ ko,
                                                   float* __restrict__ kc,
                                                   float* __restrict__ vc) {
  const int s = blockIdx.x, tid = threadIdx.x;
  const float4* r4 = (const float4*)(QKV + (size_t)s * NQKV);
  const float qscale = 0.08838834764831845f;  // 1/sqrt(128) folded into Q
#pragma unroll
  for (int it = 0; it < 5; ++it) {
    int i = it * 256 + tid;
    float4 x = r4[i];
    int e = i * 4;            // flat float index within row
    int d = e & 127;          // dim within head (heads are 128-aligned)
    float4 c = *(const float4*)&cosb[(size_t)s * HDIM + d];
    float4 si = *(const float4*)&sinb[(size_t)s * HDIM + d];
    float o0 = x.x * c.x - x.y * si.x;
    float o1 = x.y * c.y + x.x * si.y;
    float o2 = x.z * c.z - x.w * si.z;
    float o3 = x.w * c.w + x.z * si.w;
    if (e < NHEAD * HDIM) {
      int hh = e >> 7;
      s16x4 ov;
      ov[0] = f2bf(o0 * qscale); ov[1] = f2bf(o1 * qscale);
      ov[2] = f2bf(o2 * qscale); ov[3] = f2bf(o3 * qscale);
      *(s16x4*)&qo[((size_t)hh * S_LEN + s) * HDIM + d] = ov;
    } else {
      int ek = e - NHEAD * HDIM;
      int g = ek >> 7;
      s16x4 ov;
      ov[0] = f2bf(o0); ov[1] = f2bf(o1); ov[2] = f2bf(o2); ov[3] = f2bf(o3);
      *(s16x4*)&ko[((size_t)g * S_LEN + s) * HDIM + d] = ov;
      *(float4*)&kc[(size_t)s * (NKV * HDIM) + ek] = make_float4(o0, o1, o2, o3);
    }
  }
  // zero cache tails: tail float4 count = (MAXSEQ-S_LEN)*NKV*HDIM/4 = 524288 = 2048*256
  {
    const size_t base = (size_t)S_LEN * NKV * HDIM;
    const size_t i = (size_t)s * 256 + tid;
    const float4 z = make_float4(0.f, 0.f, 0.f, 0.f);
    ((float4*)(kc + base))[i] = z;
    ((float4*)(vc + base))[i] = z;
  }
}

// ---------------- GQA causal flash attention v2 ----------------
#define TKEY 128
__global__ __launch_bounds__(256, 1) void attn_kernel(const short* __restrict__ Q,
                                                      const short* __restrict__ Kb,
                                                      const short* __restrict__ Vt,
                                                      short* __restrict__ out) {
  extern __shared__ __align__(16) short smem[];
  short* Ks = smem;            // 2 * 128*128
  short* Vs = smem + 32768;    // 2 * 128*128
  short* Ps = smem + 65536;    // 4 waves * 32*32
  const int tid = threadIdx.x;
  const int lane = tid & 63, wave = tid >> 6;
  const int lrow = lane & 15, quad = lane >> 4;
  const int g = blockIdx.x & 7, p = blockIdx.x >> 3;
  const int h = g * 4 + wave;
  const float L2E = 1.44269504f;
  const short* Kg = Kb + (size_t)g * S_LEN * HDIM;
  const short* Vg = Vt + (size_t)g * HDIM * S_LEN;
  short* Pw = Ps + wave * 1024;

#pragma unroll 1
  for (int ph = 0; ph < 2; ++ph) {
    const int qt = ph ? (63 - p) : p;
    const int nt = (qt >> 2) + 1;  // # of 128-key tiles

    bf16x8 qf[2][4];
#pragma unroll
    for (int i = 0; i < 2; ++i)
#pragma unroll
      for (int kf = 0; kf < 4; ++kf)
        qf[i][kf] = *(const bf16x8*)&Q[((size_t)h * S_LEN + qt * 32 + i * 16 + lrow) * HDIM + kf * 32 + quad * 8];

    f32x4 O[2][8] = {};
    float mrun[2][4], lrun[2][4];
#pragma unroll
    for (int i = 0; i < 2; ++i)
#pragma unroll
      for (int r = 0; r < 4; ++r) { mrun[i][r] = -1e30f; lrun[i][r] = 0.f; }

    // stage tile 0 into buffer 0
#pragma unroll
    for (int ii = 0; ii < 8; ++ii) {
      int s = (wave * 8 + ii) * 64 + lane;
      int r = s >> 4, gg = (s & 15) ^ (r & 15);
      gload_lds16(Kg + (size_t)r * HDIM + gg * 8, Ks + (wave * 8 + ii) * 512);
    }
#pragma unroll
    for (int ii = 0; ii < 8; ++ii) {
      int s = (wave * 8 + ii) * 64 + lane;
      int d = s >> 4, kg = (s & 15) ^ (d & 15);
      gload_lds16(Vg + (size_t)d * S_LEN + kg * 8, Vs + (wave * 8 + ii) * 512);
    }
    __syncthreads();

#pragma unroll 1
    for (int t = 0; t < nt; ++t) {
      const int bsel = t & 1;
      if (t + 1 < nt) {
        const int kb2 = (t + 1) * TKEY, o = (1 - bsel) * 16384;
#pragma unroll
        for (int ii = 0; ii < 8; ++ii) {
          int s = (wave * 8 + ii) * 64 + lane;
          int r = s >> 4, gg = (s & 15) ^ (r & 15);
          gload_lds16(Kg + (size_t)(kb2 + r) * HDIM + gg * 8, Ks + o + (wave * 8 + ii) * 512);
        }
#pragma unroll
        for (int ii = 0; ii < 8; ++ii) {
          int s = (wave * 8 + ii) * 64 + lane;
          int d = s >> 4, kg = (s & 15) ^ (d & 15);
          gload_lds16(Vg + (size_t)d * S_LEN + kb2 + kg * 8, Vs + o + (wave * 8 + ii) * 512);
        }
      }
      const short* Kc = Ks + bsel * 16384;
      const short* Vc = Vs + bsel * 16384;

      // ---- QK^T: 32 rows x 128 keys ----
      f32x4 sc[2][8] = {};
#pragma unroll
      for (int c = 0; c < 8; ++c) {
        int r = c * 16 + lrow;
#pragma unroll
        for (int kf = 0; kf < 4; ++kf) {
          int slot = r * 16 + ((kf * 4 + quad) ^ lrow);
          bf16x8 kfr = *(const bf16x8*)&Kc[slot * 8];
          sc[0][c] = __builtin_amdgcn_mfma_f32_16x16x32_bf16(qf[0][kf], kfr, sc[0][c], 0, 0, 0);
          sc[1][c] = __builtin_amdgcn_mfma_f32_16x16x32_bf16(qf[1][kf], kfr, sc[1][c], 0, 0, 0);
        }
      }

      // ---- online softmax ----
      const int kb = t * TKEY;
      const bool last = (t == nt - 1);
#pragma unroll
      for (int i = 0; i < 2; ++i) {
        if (last) {
#pragma unroll
          for (int c = 0; c < 8; ++c) {
            int key = kb + c * 16 + lrow;
#pragma unroll
            for (int r = 0; r < 4; ++r) {
              int row = qt * 32 + i * 16 + quad * 4 + r;
              if (key > row) sc[i][c][r] = -1e30f;
            }
          }
        }
        float tm[4];
#pragma unroll
        for (int r = 0; r < 4; ++r) tm[r] = sc[i][0][r];
#pragma unroll
        for (int c = 1; c < 8; ++c)
#pragma unroll
          for (int r = 0; r < 4; ++r) tm[r] = fmaxf(tm[r], sc[i][c][r]);
#pragma unroll
        for (int msk = 1; msk <= 8; msk <<= 1)
#pragma unroll
          for (int r = 0; r < 4; ++r) tm[r] = fmaxf(tm[r], __shfl_xor(tm[r], msk, 64));
#pragma unroll
        for (int r = 0; r < 4; ++r) {
          float nm = fmaxf(mrun[i][r], tm[r]);
          float alpha = exp2f((mrun[i][r] - nm) * L2E);
          mrun[i][r] = nm;
          lrun[i][r] *= alpha;
#pragma unroll
          for (int jd = 0; jd < 8; ++jd) O[i][jd][r] *= alpha;
        }
        float rs[4] = {0.f, 0.f, 0.f, 0.f};
#pragma unroll
        for (int c = 0; c < 8; ++c)
#pragma unroll
          for (int r = 0; r < 4; ++r) {
            float pv = exp2f((sc[i][c][r] - mrun[i][r]) * L2E);
            sc[i][c][r] = pv;
            rs[r] += pv;
          }
#pragma unroll
        for (int msk = 1; msk <= 8; msk <<= 1)
#pragma unroll
          for (int r = 0; r < 4; ++r) rs[r] += __shfl_xor(rs[r], msk, 64);
#pragma unroll
        for (int r = 0; r < 4; ++r) lrun[i][r] += rs[r];
      }

      // ---- P·V in 32-key chunks ----
#pragma unroll
      for (int ks = 0; ks < 4; ++ks) {
#pragma unroll
        for (int i = 0; i < 2; ++i)
#pragma unroll
          for (int cc = 0; cc < 2; ++cc) {
            int c = ks * 2 + cc;
            int kg = cc * 2 + (lrow >> 3), off = lrow & 7;
#pragma unroll
            for (int r = 0; r < 4; ++r) {
              int q2 = i * 16 + quad * 4 + r;
              int slot = q2 * 4 + (kg ^ (q2 & 3) ^ ((q2 >> 2) & 3));
              Pw[slot * 8 + off] = f2bf(sc[i][c][r]);
            }
          }
        bf16x8 pa[2];
#pragma unroll
        for (int i = 0; i < 2; ++i) {
          int q2 = i * 16 + lrow;
          int slot = q2 * 4 + (quad ^ (q2 & 3) ^ ((q2 >> 2) & 3));
          pa[i] = *(const bf16x8*)&Pw[slot * 8];
        }
#pragma unroll
        for (int jd = 0; jd < 8; ++jd) {
          int d = jd * 16 + lrow;
          int slotv = d * 16 + ((ks * 4 + quad) ^ lrow);
          bf16x8 vb = *(const bf16x8*)&Vc[slotv * 8];
          O[0][jd] = __builtin_amdgcn_mfma_f32_16x16x32_bf16(pa[0], vb, O[0][jd], 0, 0, 0);
          O[1][jd] = __builtin_amdgcn_mfma_f32_16x16x32_bf16(pa[1], vb, O[1][jd], 0, 0, 0);
        }
      }
      __syncthreads();
    }

    // ---- epilogue ----
#pragma unroll
    for (int i = 0; i < 2; ++i)
#pragma unroll
      for (int r = 0; r < 4; ++r) {
        float inv = 1.f / lrun[i][r];
        int row = qt * 32 + i * 16 + quad * 4 + r;
#pragma unroll
        for (int jd = 0; jd < 8; ++jd)
          out[(size_t)row * DMODEL + h * HDIM + jd * 16 + lrow] = f2bf(O[i][jd][r] * inv);
      }
    __syncthreads();  // Ks/Vs safe for next phase's staging
  }
}

extern "C" void kernel_launch(void* const* d_in, const int* in_sizes, int n_in,
                              void* d_out, int out_size, void* d_ws, size_t ws_size,
                              hipStream_t stream) {
  const float* hs   = (const float*)d_in[0];
  const float* cosb = (const float*)d_in[1];
  const float* sinb = (const float*)d_in[2];
  const float* Wq   = (const float*)d_in[5];
  const float* Wk   = (const float*)d_in[6];
  const float* Wv   = (const float*)d_in[7];
  const float* Wo   = (const float*)d_in[8];
  const float* rmsw = (const float*)d_in[9];

  float* outp = (float*)d_out;
  float* kc = outp + (size_t)S_LEN * DMODEL;
  float* vc = kc + (size_t)MAXSEQ * NKV * HDIM;

  char* p = (char*)d_ws;
  short* h_bf  = (short*)p; p += (size_t)S_LEN * DMODEL * 2;
  short* WqkvT = (short*)p; p += (size_t)NQKV * DMODEL * 2;
  short* WoT   = (short*)p; p += (size_t)DMODEL * DMODEL * 2;
  float* QKV   = (float*)p; p += (size_t)S_LEN * NQKV * 4;
  short* q_bf  = (short*)p; p += (size_t)NHEAD * S_LEN * HDIM * 2;
  short* k_bf  = (short*)p; p += (size_t)NKV * S_LEN * HDIM * 2;
  short* vt_bf = (short*)p; p += (size_t)NKV * HDIM * S_LEN * 2;
  short* attn_bf = h_bf;  // alias: h consumed by gemm1 before attention writes

  const int ATTN_LDS = 139264;  // 64KB K dbuf + 64KB V dbuf + 8KB P
  hipFuncSetAttribute(reinterpret_cast<const void*>(attn_kernel),
                      hipFuncAttributeMaxDynamicSharedMemorySize, ATTN_LDS);
  const int GEMM_LDS3 = 65536 + 3 * 16384;  // 112 KiB (NF=3)
  const int GEMM_LDS2 = 65536 + 2 * 16384;  // 96 KiB  (NF=2)
  hipFuncSetAttribute(reinterpret_cast<const void*>(gemm256<3>),
                      hipFuncAttributeMaxDynamicSharedMemorySize, GEMM_LDS3);
  hipFuncSetAttribute(reinterpret_cast<const void*>(gemm256<2>),
                      hipFuncAttributeMaxDynamicSharedMemorySize, GEMM_LDS2);

  rmsnorm_kernel<<<S_LEN, 256, 0, stream>>>(hs, rmsw, h_bf);
  cast_transpose_all<<<dim3(128, 128, 4), dim3(32, 8), 0, stream>>>(Wq, Wk, Wv, Wo, WqkvT, WoT);
  // QKV GEMM: N=6144, BN=192 -> grid 32x8 = 256 blocks (full chip)
  gemm256<3><<<dim3(NQKV / 192, S_LEN / 256), 512, GEMM_LDS3, stream>>>(h_bf, WqkvT, QKV, nullptr, S_LEN, NQKV, DMODEL);
  rope_kernel<<<S_LEN, 256, 0, stream>>>(QKV, cosb, sinb, q_bf, k_bf, kc, vc);
  v_transpose<<<dim3(HDIM / 32, S_LEN / 32, NKV), dim3(32, 8), 0, stream>>>(QKV, vc, vt_bf);
  attn_kernel<<<256, 256, ATTN_LDS, stream>>>(q_bf, k_bf, vt_bf, attn_bf);
  // Wo GEMM: N=4096, BN=128 -> grid 32x8 = 256 blocks (full chip)
  gemm256<2><<<dim3(DMODEL / 128, S_LEN / 256), 512, GEMM_LDS2, stream>>>(attn_bf, WoT, outp, hs, S_LEN, DMODEL, DMODEL);
}